// Round 8
// baseline (768.620 us; speedup 1.0000x reference)
//
#include <hip/hip_runtime.h>
#include <hip/hip_cooperative_groups.h>
#include <hip/hip_bf16.h>
#include <math.h>

#define N_NODES 50000
#define N_EDGES 800000
#define NUM_GRAPHS 64
#define NPAD 50048          // multiple of 64
#define KPAD0 288           // 261 padded to multiple of 32
#define PSPLIT 16
#define MAXDEG 64           // Poisson(16): P(deg>64) ~ 1e-20

#define G0_GRID    (NPAD / 32)                  // 1564: (row-tile, col-half) pairs
#define LAYER_TILES (NPAD / 32)                 // 1564
#define PREPW_TOT  (128 * KPAD0 + 6 * 128 * 64) // 86016
#define PREPW_GRID ((PREPW_TOT + 255) / 256)    // 336
#define CONV_GRID  (NPAD * (KPAD0 / 8) / 256)   // 7038: X->bf16 packing
#define PREP2_GRID (CONV_GRID + PREPW_GRID)     // 7374

// XCD-sliced scatter: slice s handles dst in [s*NPS, (s+1)*NPS)
#define SLICES 8
#define NPS 6250
#define SCHUNK 2048
#define SCHUNKS ((N_EDGES + SCHUNK - 1) / SCHUNK)   // 391
#define SCAT_GRID (SCHUNKS * SLICES)                // 3128

namespace cg = cooperative_groups;

typedef __attribute__((ext_vector_type(8))) short short8;
typedef __attribute__((ext_vector_type(4))) float f32x4;

__device__ __forceinline__ float gelu_f(float v) {
    return 0.5f * v * (1.0f + erff(v * 0.70710678118654752440f));
}

__device__ __forceinline__ float half_sum32(float v) {
    v += __shfl_xor(v, 1); v += __shfl_xor(v, 2); v += __shfl_xor(v, 4);
    v += __shfl_xor(v, 8); v += __shfl_xor(v, 16);
    return v;
}

__device__ __forceinline__ float group_sum8(float v) {
    v += __shfl_xor(v, 1); v += __shfl_xor(v, 2); v += __shfl_xor(v, 4);
    return v;
}

__device__ __forceinline__ unsigned short f2bf(float f) {
    unsigned int u = __float_as_uint(f);
    unsigned int r = (u + 0x7fffu + ((u >> 16) & 1u)) >> 16;
    return (unsigned short)r;
}

__device__ __forceinline__ float bf_lo(unsigned int u) {
    return __uint_as_float(u << 16);
}
__device__ __forceinline__ float bf_hi(unsigned int u) {
    return __uint_as_float(u & 0xffff0000u);
}

// ---------------- prep2: X->bf16 pack + weight transpose (streaming) ----------------

__global__ __launch_bounds__(256) void k_prep2(
        const float* __restrict__ X, unsigned short* __restrict__ Xbf,
        const float* __restrict__ Wl0, const float* __restrict__ Wr0,
        const float* __restrict__ Wl, const float* __restrict__ Wr,
        unsigned short* __restrict__ Bt0, unsigned short* __restrict__ BtR) {
    const int blk = blockIdx.x;
    const int tid = threadIdx.x;
    if (blk < CONV_GRID) {
        int t = blk * 256 + tid;                 // short8 group index
        int node = t / (KPAD0 / 8);              // 36 groups per row
        int k8 = (t - node * (KPAD0 / 8)) * 8;
        short8 v8;
        if (node < N_NODES) {
            #pragma unroll
            for (int j = 0; j < 8; ++j) {
                int k = k8 + j;
                float val = (k < 261) ? __builtin_nontemporal_load(&X[(size_t)node * 261 + k]) : 0.0f;
                v8[j] = (short)f2bf(val);
            }
        } else {
            #pragma unroll
            for (int j = 0; j < 8; ++j) v8[j] = 0;
        }
        *(short8*)&Xbf[(size_t)node * KPAD0 + k8] = v8;
        return;
    }
    int idx = (blk - CONV_GRID) * 256 + tid;
    const int n0 = 128 * KPAD0;
    if (idx < n0) {
        int j = idx / KPAD0, k = idx - j * KPAD0;
        float v = 0.0f;
        if (k < 261) v = (j < 64) ? Wl0[k * 64 + j] : Wr0[k * 64 + (j - 64)];
        Bt0[idx] = f2bf(v);
    } else if (idx < PREPW_TOT) {
        int r = idx - n0;
        int l = r >> 13;
        int rr = r & 8191;
        int j = rr >> 6, k = rr & 63;
        float v = (j < 64) ? Wl[l * 4096 + k * 64 + j] : Wr[l * 4096 + k * 64 + (j - 64)];
        BtR[r] = f2bf(v);
    }
}

// ---------------- XCD-sliced adjacency scatter ----------------
// slice = blk & 7 (round-robin blockIdx -> XCD keeps each slice's col64/deg
// window resident in one XCD's L2), chunk = blk >> 3.

__global__ __launch_bounds__(256) void k_scat(
        const int* __restrict__ src, const int* __restrict__ dst,
        int* __restrict__ deg, unsigned short* __restrict__ col64) {
    const int s = blockIdx.x & (SLICES - 1);
    const int c = blockIdx.x >> 3;
    const int base = c * SCHUNK;
    const int lim = min(base + SCHUNK, N_EDGES);
    for (int i = base + (int)threadIdx.x; i < lim; i += 256) {
        int d = __builtin_nontemporal_load(&dst[i]);
        if (d / NPS == s) {
            int sv = __builtin_nontemporal_load(&src[i]);
            int pos = atomicAdd(&deg[d], 1);
            if (pos < MAXDEG) col64[(d << 6) + pos] = (unsigned short)sv;
        }
    }
}

// ---------------- proj GEMM: [U|V] = Xbf @ [Wl0|Wr0] ----------------

__global__ __launch_bounds__(256) void k_gemm0(
        const unsigned short* __restrict__ Xbf, const unsigned short* __restrict__ Bt0,
        unsigned short* __restrict__ U, float* __restrict__ V) {
    __shared__ __align__(16) unsigned short sB[64 * 296];   // 296 = 288 + 8 pad
    const int tid = threadIdx.x;
    const int lane = tid & 63, wid = tid >> 6;
    const int l16 = lane & 15, quad = lane >> 4;
    const int ch = blockIdx.x & 1;          // 0: U cols 0-63, 1: V cols 64-127
    const int m0 = (blockIdx.x >> 1) * 64;
    #pragma unroll
    for (int k = 0; k < 9; ++k) {           // 64 rows * 36 groups = 2304
        int g = k * 256 + tid;
        int row = g / 36;
        int part = (g - row * 36) * 8;
        *(short8*)&sB[row * 296 + part] =
            *(const short8*)&Bt0[(size_t)(ch * 64 + row) * KPAD0 + part];
    }
    f32x4 acc[4];
    #pragma unroll
    for (int j = 0; j < 4; ++j) { acc[j][0] = 0.f; acc[j][1] = 0.f; acc[j][2] = 0.f; acc[j][3] = 0.f; }
    const unsigned short* xr = Xbf + (size_t)(m0 + wid * 16 + l16) * KPAD0 + quad * 8;
    __syncthreads();
    for (int kc = 0; kc < KPAD0; kc += 32) {
        short8 af = *(const short8*)(xr + kc);
        #pragma unroll
        for (int j = 0; j < 4; ++j) {
            short8 bfv = *(const short8*)&sB[(j * 16 + l16) * 296 + kc + quad * 8];
            acc[j] = __builtin_amdgcn_mfma_f32_16x16x32_bf16(af, bfv, acc[j], 0, 0, 0);
        }
    }
    const int rbase = m0 + wid * 16 + quad * 4;
    if (ch == 0) {
        #pragma unroll
        for (int j = 0; j < 4; ++j)
            #pragma unroll
            for (int r = 0; r < 4; ++r)
                U[(size_t)(rbase + r) * 64 + j * 16 + l16] = f2bf(acc[j][r]);
    } else {
        #pragma unroll
        for (int j = 0; j < 4; ++j)
            #pragma unroll
            for (int r = 0; r < 4; ++r)
                V[(size_t)(rbase + r) * 64 + j * 16 + l16] = acc[j][r];
    }
}

// ---------------- cooperative megakernel: all 7 layers, grid.sync between ----------------
// Per layer: sB staged once (hidden under gather); per tile: gather+LN ->
// park sA -> one __syncthreads -> K=64 MFMA GEMM. Layer 6 folds pooling
// (atomicAdd partial sums) and skips h/U/V writes. Grid sized by runtime
// occupancy query; tiles covered by grid-stride loop.

__global__ __launch_bounds__(256) void k_net(
        unsigned short* __restrict__ Ua, float* __restrict__ Va,
        unsigned short* __restrict__ Ub, float* __restrict__ Vb,
        unsigned short* __restrict__ h,
        const int* __restrict__ deg, const unsigned short* __restrict__ col64,
        const float* __restrict__ bl0, const float* __restrict__ g0,
        const float* __restrict__ bet0,
        const float* __restrict__ blR, const float* __restrict__ gR,
        const float* __restrict__ betR,
        const unsigned short* __restrict__ BtR,
        const int* __restrict__ batch, float* __restrict__ partial) {
    __shared__ __align__(16) unsigned short sA[2 * 32 * 32];  // [chunk][row][32k]
    __shared__ __align__(16) unsigned short sB[128 * 72];     // 72 = 64 + 8 pad
    cg::grid_group grid = cg::this_grid();
    const int tid = threadIdx.x;
    const int lane = tid & 63, wid = tid >> 6;
    const int sub = lane >> 3, hl = lane & 7;
    const int base = lane & 56;

    for (int L = 0; L < 7; ++L) {
        const int have_gemm = (L < 6);
        const int residual = (L > 0);
        const unsigned short* U_in = (L & 1) ? Ub : Ua;
        const float* V_in = (L & 1) ? Vb : Va;
        unsigned short* U_out = (L & 1) ? Ua : Ub;
        float* V_out = (L & 1) ? Va : Vb;
        const float* bias = L ? (blR + (size_t)(L - 1) * 64) : bl0;
        const float* gam  = L ? (gR  + (size_t)(L - 1) * 64) : g0;
        const float* bet  = L ? (betR + (size_t)(L - 1) * 64) : bet0;
        const uint4* __restrict__ Up = (const uint4*)U_in;

        if (have_gemm) {
            const unsigned short* Bt = BtR + (size_t)L * 128 * 64;
            #pragma unroll
            for (int k = 0; k < 4; ++k) {       // 128 rows * 8 groups = 1024
                int g = k * 256 + tid;
                int row = g >> 3, part = (g & 7) * 8;
                *(short8*)&sB[row * 72 + part] = *(const short8*)&Bt[(size_t)row * 64 + part];
            }
        }

        for (int tile = blockIdx.x; tile < LAYER_TILES; tile += gridDim.x) {
            const int m0 = tile * 32;
            const int nl = wid * 8 + sub;          // 0..31: node-in-tile
            const int node = m0 + nl;
            const bool valid = (node < N_NODES);
            const int nd = valid ? node : 0;
            const int dg = valid ? deg[nd] : 0;
            const int cnt = min(dg, MAXDEG);
            uint4 cv = make_uint4(0u, 0u, 0u, 0u);
            if (valid) cv = *(const uint4*)&col64[((size_t)nd << 6) + hl * 8];

            // hoisted independent loads: overlap their latency with the gather
            float4 v0 = make_float4(0.f, 0.f, 0.f, 0.f), v1 = v0;
            if (valid) {
                v0 = *(const float4*)&V_in[(size_t)nd * 64 + 8 * hl];
                v1 = *(const float4*)&V_in[(size_t)nd * 64 + 8 * hl + 4];
            }
            uint4 hu = make_uint4(0u, 0u, 0u, 0u);
            if (residual && valid) hu = ((const uint4*)h)[(size_t)nd * 8 + hl];

            float s0 = 0.f, s1 = 0.f, s2 = 0.f, s3 = 0.f, s4 = 0.f, s5 = 0.f, s6 = 0.f, s7 = 0.f;
            for (int b = 0; b * 8 < cnt; b += 2) {
                #pragma unroll
                for (int hh = 0; hh < 2; ++hh) {
                    const int sl = base + b + hh;
                    unsigned int p0 = (unsigned int)__shfl((int)cv.x, sl);
                    unsigned int p1 = (unsigned int)__shfl((int)cv.y, sl);
                    unsigned int p2 = (unsigned int)__shfl((int)cv.z, sl);
                    unsigned int p3 = (unsigned int)__shfl((int)cv.w, sl);
                    const int eb = (b + hh) * 8;
                    int c[8];
                    c[0] = (int)(p0 & 0xffffu); c[1] = (int)(p0 >> 16);
                    c[2] = (int)(p1 & 0xffffu); c[3] = (int)(p1 >> 16);
                    c[4] = (int)(p2 & 0xffffu); c[5] = (int)(p2 >> 16);
                    c[6] = (int)(p3 & 0xffffu); c[7] = (int)(p3 >> 16);
                    #pragma unroll
                    for (int i = 0; i < 8; ++i) {
                        uint4 u = (eb + i < cnt) ? Up[(size_t)c[i] * 8 + hl] : make_uint4(0u, 0u, 0u, 0u);
                        s0 += bf_lo(u.x); s1 += bf_hi(u.x);
                        s2 += bf_lo(u.y); s3 += bf_hi(u.y);
                        s4 += bf_lo(u.z); s5 += bf_hi(u.z);
                        s6 += bf_lo(u.w); s7 += bf_hi(u.w);
                    }
                }
            }
            const float id = 1.0f / fmaxf((float)dg, 1.0f);
            const float4 b0 = *(const float4*)&bias[8 * hl];
            const float4 b1 = *(const float4*)&bias[8 * hl + 4];
            float f0 = gelu_f(s0 * id + b0.x + v0.x);
            float f1 = gelu_f(s1 * id + b0.y + v0.y);
            float f2 = gelu_f(s2 * id + b0.z + v0.z);
            float f3 = gelu_f(s3 * id + b0.w + v0.w);
            float f4 = gelu_f(s4 * id + b1.x + v1.x);
            float f5 = gelu_f(s5 * id + b1.y + v1.y);
            float f6 = gelu_f(s6 * id + b1.z + v1.z);
            float f7 = gelu_f(s7 * id + b1.w + v1.w);
            float mu = group_sum8(((f0 + f1) + (f2 + f3)) + ((f4 + f5) + (f6 + f7))) * 0.015625f;
            float d0 = f0 - mu, d1 = f1 - mu, d2 = f2 - mu, d3 = f3 - mu;
            float d4 = f4 - mu, d5 = f5 - mu, d6 = f6 - mu, d7 = f7 - mu;
            float var = group_sum8(((d0 * d0 + d1 * d1) + (d2 * d2 + d3 * d3)) +
                                   ((d4 * d4 + d5 * d5) + (d6 * d6 + d7 * d7))) * 0.015625f;
            float rs = rsqrtf(var + 1e-5f);
            const float4 g0v = *(const float4*)&gam[8 * hl];
            const float4 g1v = *(const float4*)&gam[8 * hl + 4];
            const float4 e0v = *(const float4*)&bet[8 * hl];
            const float4 e1v = *(const float4*)&bet[8 * hl + 4];
            f0 = d0 * rs * g0v.x + e0v.x;
            f1 = d1 * rs * g0v.y + e0v.y;
            f2 = d2 * rs * g0v.z + e0v.z;
            f3 = d3 * rs * g0v.w + e0v.w;
            f4 = d4 * rs * g1v.x + e1v.x;
            f5 = d5 * rs * g1v.y + e1v.y;
            f6 = d6 * rs * g1v.z + e1v.z;
            f7 = d7 * rs * g1v.w + e1v.w;
            if (residual && valid) {
                f0 += bf_lo(hu.x); f1 += bf_hi(hu.x);
                f2 += bf_lo(hu.y); f3 += bf_hi(hu.y);
                f4 += bf_lo(hu.z); f5 += bf_hi(hu.z);
                f6 += bf_lo(hu.w); f7 += bf_hi(hu.w);
            }

            if (L == 6) {
                // ---- last layer: fold graph pooling ----
                const int myg = valid ? batch[nd] : -1;
                const int i_lo = (m0 < N_NODES) ? m0 : (N_NODES - 1);
                const int i_hi = (m0 + 31 < N_NODES) ? (m0 + 31) : (N_NODES - 1);
                const int g_lo = batch[i_lo];
                const int g_hi = batch[i_hi];
                const int split = tile & (PSPLIT - 1);
                for (int g = g_lo; g <= g_hi; ++g) {
                    const bool mine = (myg == g);
                    float p0 = mine ? f0 : 0.f, p1 = mine ? f1 : 0.f;
                    float p2 = mine ? f2 : 0.f, p3 = mine ? f3 : 0.f;
                    float p4 = mine ? f4 : 0.f, p5 = mine ? f5 : 0.f;
                    float p6 = mine ? f6 : 0.f, p7 = mine ? f7 : 0.f;
                    p0 += __shfl_xor(p0, 8);  p1 += __shfl_xor(p1, 8);
                    p2 += __shfl_xor(p2, 8);  p3 += __shfl_xor(p3, 8);
                    p4 += __shfl_xor(p4, 8);  p5 += __shfl_xor(p5, 8);
                    p6 += __shfl_xor(p6, 8);  p7 += __shfl_xor(p7, 8);
                    p0 += __shfl_xor(p0, 16); p1 += __shfl_xor(p1, 16);
                    p2 += __shfl_xor(p2, 16); p3 += __shfl_xor(p3, 16);
                    p4 += __shfl_xor(p4, 16); p5 += __shfl_xor(p5, 16);
                    p6 += __shfl_xor(p6, 16); p7 += __shfl_xor(p7, 16);
                    p0 += __shfl_xor(p0, 32); p1 += __shfl_xor(p1, 32);
                    p2 += __shfl_xor(p2, 32); p3 += __shfl_xor(p3, 32);
                    p4 += __shfl_xor(p4, 32); p5 += __shfl_xor(p5, 32);
                    p6 += __shfl_xor(p6, 32); p7 += __shfl_xor(p7, 32);
                    if (sub == 0) {
                        float* dp = &partial[((size_t)g * PSPLIT + split) * 64 + 8 * hl];
                        atomicAdd(dp + 0, p0); atomicAdd(dp + 1, p1);
                        atomicAdd(dp + 2, p2); atomicAdd(dp + 3, p3);
                        atomicAdd(dp + 4, p4); atomicAdd(dp + 5, p5);
                        atomicAdd(dp + 6, p6); atomicAdd(dp + 7, p7);
                    }
                }
            } else {
                uint4 outw;
                outw.x = (unsigned int)f2bf(f0) | ((unsigned int)f2bf(f1) << 16);
                outw.y = (unsigned int)f2bf(f2) | ((unsigned int)f2bf(f3) << 16);
                outw.z = (unsigned int)f2bf(f4) | ((unsigned int)f2bf(f5) << 16);
                outw.w = (unsigned int)f2bf(f6) | ((unsigned int)f2bf(f7) << 16);
                if (valid) ((uint4*)h)[(size_t)nd * 8 + hl] = outw;
                // park LN output in LDS: chunk=hl>>2, k-offset=(hl&3)*8
                *(uint4*)&sA[(((hl >> 2) * 32 + nl) << 5) + (hl & 3) * 8] = outw;
                __syncthreads();   // covers sA park + sB staging

                // ---- GEMM: [U_out | V_out](rows m0..m0+31) = sA @ sB, K=64 ----
                const int l16 = lane & 15, quad = lane >> 4;
                const int wrow = wid & 1, colh = wid >> 1;
                f32x4 acc[4];
                #pragma unroll
                for (int j = 0; j < 4; ++j) { acc[j][0] = 0.f; acc[j][1] = 0.f; acc[j][2] = 0.f; acc[j][3] = 0.f; }
                #pragma unroll
                for (int kc = 0; kc < 64; kc += 32) {
                    short8 af = *(const short8*)&sA[(((kc >> 5) * 32 + wrow * 16 + l16) << 5) + quad * 8];
                    #pragma unroll
                    for (int j = 0; j < 4; ++j) {
                        short8 bfv = *(const short8*)&sB[(colh * 64 + j * 16 + l16) * 72 + kc + quad * 8];
                        acc[j] = __builtin_amdgcn_mfma_f32_16x16x32_bf16(af, bfv, acc[j], 0, 0, 0);
                    }
                }
                const int rbase = m0 + wrow * 16 + quad * 4;
                if (colh == 0) {
                    #pragma unroll
                    for (int j = 0; j < 4; ++j)
                        #pragma unroll
                        for (int r = 0; r < 4; ++r)
                            U_out[(size_t)(rbase + r) * 64 + j * 16 + l16] = f2bf(acc[j][r]);
                } else {
                    #pragma unroll
                    for (int j = 0; j < 4; ++j)
                        #pragma unroll
                        for (int r = 0; r < 4; ++r)
                            V_out[(size_t)(rbase + r) * 64 + j * 16 + l16] = acc[j][r];
                }
                __syncthreads();   // protect sA before next tile's park
            }
        }
        grid.sync();
    }
}

// ---------------- MLP head (folds pool stage 2) ----------------

__global__ __launch_bounds__(1024) void k_head(const float* __restrict__ partial,
                                               const float* __restrict__ M0, const float* __restrict__ mb0,
                                               const float* __restrict__ mg0, const float* __restrict__ mbeta0,
                                               const float* __restrict__ M, const float* __restrict__ mb,
                                               const float* __restrict__ mg, const float* __restrict__ mbeta,
                                               const float* __restrict__ Wf, const float* __restrict__ bf,
                                               float* __restrict__ out) {
    __shared__ float sP[64 * 64];
    __shared__ float sA[64 * 33];
    __shared__ float sB[64 * 33];
    const int tx = threadIdx.x, ty = threadIdx.y;
    const int tid = ty * 32 + tx;
    for (int i = tid; i < 64 * 64; i += 1024) {
        int g = i >> 6, f = i & 63;
        float s = 0.0f;
        #pragma unroll
        for (int s2 = 0; s2 < PSPLIT; ++s2) s += partial[(size_t)(g * PSPLIT + s2) * 64 + f];
        sP[i] = s;
    }
    __syncthreads();
    #pragma unroll
    for (int rr = 0; rr < 2; ++rr) {
        int r = ty + rr * 32;
        float a = mb0[tx];
        for (int k = 0; k < 64; ++k) a += sP[r * 64 + k] * M0[k * 32 + tx];
        a = gelu_f(a);
        float mu = half_sum32(a) * (1.0f / 32.0f);
        float d = a - mu;
        float var = half_sum32(d * d) * (1.0f / 32.0f);
        a = d * rsqrtf(var + 1e-5f) * mg0[tx] + mbeta0[tx];
        sA[r * 33 + tx] = a;
    }
    __syncthreads();
    float* cur = sA;
    float* nxt = sB;
    for (int L = 0; L < 3; ++L) {
        const float* Mi = M + L * 32 * 32;
        const float* mbi = mb + L * 32;
        const float* mgi = mg + L * 32;
        const float* mbetai = mbeta + L * 32;
        #pragma unroll
        for (int rr = 0; rr < 2; ++rr) {
            int r = ty + rr * 32;
            float a = mbi[tx];
            for (int k = 0; k < 32; ++k) a += cur[r * 33 + k] * Mi[k * 32 + tx];
            a = gelu_f(a);
            float mu = half_sum32(a) * (1.0f / 32.0f);
            float d = a - mu;
            float var = half_sum32(d * d) * (1.0f / 32.0f);
            a = d * rsqrtf(var + 1e-5f) * mgi[tx] + mbetai[tx] + cur[r * 33 + tx];
            nxt[r * 33 + tx] = a;
        }
        __syncthreads();
        float* t = cur; cur = nxt; nxt = t;
    }
    #pragma unroll
    for (int rr = 0; rr < 2; ++rr) {
        int r = ty + rr * 32;
        float p = cur[r * 33 + tx] * Wf[tx];
        p = half_sum32(p);
        if (tx == 0) out[r] = p + bf[0];
    }
}

// ---------------- host launcher ----------------

extern "C" void kernel_launch(void* const* d_in, const int* in_sizes, int n_in,
                              void* d_out, int out_size, void* d_ws, size_t ws_size,
                              hipStream_t stream) {
    const int N = N_NODES;
    const int E = N_EDGES;

    const float* x    = (const float*)d_in[0];
    const int* eidx   = (const int*)d_in[1];
    const int* batch  = (const int*)d_in[2];
    const float* Wl0  = (const float*)d_in[3];
    const float* bl0  = (const float*)d_in[4];
    const float* Wr0  = (const float*)d_in[5];
    const float* g0   = (const float*)d_in[6];
    const float* bet0 = (const float*)d_in[7];
    const float* Wl   = (const float*)d_in[8];
    const float* bl   = (const float*)d_in[9];
    const float* Wr   = (const float*)d_in[10];
    const float* gR   = (const float*)d_in[11];
    const float* betR = (const float*)d_in[12];
    const float* M0   = (const float*)d_in[13];
    const float* mb0  = (const float*)d_in[14];
    const float* mg0  = (const float*)d_in[15];
    const float* mbe0 = (const float*)d_in[16];
    const float* M    = (const float*)d_in[17];
    const float* mb   = (const float*)d_in[18];
    const float* mg   = (const float*)d_in[19];
    const float* mbe  = (const float*)d_in[20];
    const float* Wf   = (const float*)d_in[21];
    const float* bf   = (const float*)d_in[22];

    const int* src = eidx;
    const int* dst = eidx + E;

    char* p = (char*)d_ws;
    auto alloc = [&](size_t bytes) -> void* {
        void* q = (void*)p;
        p += (bytes + 255) & ~(size_t)255;
        return q;
    };
    // deg + partial first and contiguous: one memset zeroes both
    int*   deg     = (int*)alloc((size_t)N * 4);
    float* partial = (float*)alloc((size_t)NUM_GRAPHS * PSPLIT * 64 * 4);
    unsigned short* col64 = (unsigned short*)alloc((size_t)N * MAXDEG * 2);
    unsigned short* Bt0 = (unsigned short*)alloc((size_t)128 * KPAD0 * 2);
    unsigned short* BtR = (unsigned short*)alloc((size_t)6 * 128 * 64 * 2);
    unsigned short* Xbf = (unsigned short*)alloc((size_t)NPAD * KPAD0 * 2);
    unsigned short* Ua  = (unsigned short*)alloc((size_t)NPAD * 64 * 2);
    unsigned short* Ub  = (unsigned short*)alloc((size_t)NPAD * 64 * 2);
    float* Va   = (float*)alloc((size_t)NPAD * 64 * 4);
    float* Vb   = (float*)alloc((size_t)NPAD * 64 * 4);
    unsigned short* hbuf = (unsigned short*)alloc((size_t)NPAD * 64 * 2);

    // zero deg + partial (contiguous span)
    size_t zspan = (size_t)((char*)col64 - (char*)deg);
    hipMemsetAsync(deg, 0, zspan, stream);

    // prep2: X->bf16 pack + weight transpose
    k_prep2<<<PREP2_GRID, 256, 0, stream>>>(x, Xbf, Wl0, Wr0, Wl, Wr, Bt0, BtR);

    // XCD-sliced adjacency scatter
    k_scat<<<SCAT_GRID, 256, 0, stream>>>(src, dst, deg, col64);

    // projection GEMM: [U|V] = Xbf @ [Wl0|Wr0]
    k_gemm0<<<G0_GRID, 256, 0, stream>>>(Xbf, Bt0, Ua, Va);

    // cooperative megakernel: all 7 layers in one launch, grid-sized by occupancy
    int occ = 0;
    if (hipOccupancyMaxActiveBlocksPerMultiprocessor(&occ, (const void*)k_net, 256, 0) != hipSuccess || occ <= 0)
        occ = 4;
    int grid = occ * 256;
    if (grid > LAYER_TILES) grid = LAYER_TILES;
    void* args[] = { (void*)&Ua, (void*)&Va, (void*)&Ub, (void*)&Vb, (void*)&hbuf,
                     (void*)&deg, (void*)&col64, (void*)&bl0, (void*)&g0, (void*)&bet0,
                     (void*)&bl, (void*)&gR, (void*)&betR, (void*)&BtR,
                     (void*)&batch, (void*)&partial };
    hipLaunchCooperativeKernel((void*)k_net, dim3(grid), dim3(256), args, 0, stream);

    k_head<<<1, dim3(32, 32), 0, stream>>>(partial, M0, mb0, mg0, mbe0, M, mb, mg, mbe, Wf, bf, (float*)d_out);
}

// Round 9
// 437.509 us; speedup vs baseline: 1.7568x; 1.7568x over previous
//
#include <hip/hip_runtime.h>
#include <hip/hip_bf16.h>
#include <math.h>

#define N_NODES 50000
#define N_EDGES 800000
#define NUM_GRAPHS 64
#define NPAD 50048          // multiple of 64
#define KPAD0 288           // 261 padded to multiple of 32
#define PSPLIT 16
#define MAXDEG 64           // Poisson(16): P(deg>64) ~ 1e-20

#define G0_GRID    (NPAD / 32)                  // 1564: (row-tile, col-half) pairs
#define LAYER_GRID (NPAD / 32)                  // 1564
#define PREPW_TOT  (128 * KPAD0 + 6 * 128 * 64) // 86016
#define PREPW_GRID ((PREPW_TOT + 255) / 256)    // 336
#define CONV_GRID  (NPAD * (KPAD0 / 8) / 256)   // 7038: X->bf16 packing

// XCD-sliced scatter: slice s handles dst in [s*NPS, (s+1)*NPS)
#define SLICES 8
#define NPS 6250
#define SCHUNK 2048
#define SCHUNKS ((N_EDGES + SCHUNK - 1) / SCHUNK)   // 391
#define SCAT_GRID (SCHUNKS * SLICES)                // 3128
#define FRONT_GRID (SCAT_GRID + CONV_GRID + PREPW_GRID)  // 10502

typedef __attribute__((ext_vector_type(8))) short short8;
typedef __attribute__((ext_vector_type(4))) float f32x4;

__device__ __forceinline__ float gelu_f(float v) {
    return 0.5f * v * (1.0f + erff(v * 0.70710678118654752440f));
}

__device__ __forceinline__ float half_sum32(float v) {
    v += __shfl_xor(v, 1); v += __shfl_xor(v, 2); v += __shfl_xor(v, 4);
    v += __shfl_xor(v, 8); v += __shfl_xor(v, 16);
    return v;
}

__device__ __forceinline__ float group_sum8(float v) {
    v += __shfl_xor(v, 1); v += __shfl_xor(v, 2); v += __shfl_xor(v, 4);
    return v;
}

__device__ __forceinline__ unsigned short f2bf(float f) {
    unsigned int u = __float_as_uint(f);
    unsigned int r = (u + 0x7fffu + ((u >> 16) & 1u)) >> 16;
    return (unsigned short)r;
}

__device__ __forceinline__ float bf_lo(unsigned int u) {
    return __uint_as_float(u << 16);
}
__device__ __forceinline__ float bf_hi(unsigned int u) {
    return __uint_as_float(u & 0xffff0000u);
}

// ---------------- fused front: scatter | X->bf16 conv | weight transpose ----------------
// Scatter blocks FIRST (latency-bound, span the launch); conv (streaming,
// nontemporal X reads) and weight blocks fill the memory pipes behind them.
// deg zeroed by preceding hipMemsetAsync. No LDS anywhere -> full occupancy.

__global__ __launch_bounds__(256) void k_front(
        const int* __restrict__ src, const int* __restrict__ dst,
        int* __restrict__ deg, unsigned short* __restrict__ col64,
        const float* __restrict__ X, unsigned short* __restrict__ Xbf,
        const float* __restrict__ Wl0, const float* __restrict__ Wr0,
        const float* __restrict__ Wl, const float* __restrict__ Wr,
        unsigned short* __restrict__ Bt0, unsigned short* __restrict__ BtR) {
    const int blk = blockIdx.x;
    const int tid = threadIdx.x;
    if (blk < SCAT_GRID) {
        // XCD-sliced scatter: slice = blk & 7 (round-robin blockIdx -> XCD
        // keeps each slice's col64/deg window resident in one XCD's L2)
        const int s = blk & (SLICES - 1);
        const int c = blk >> 3;
        const int base = c * SCHUNK;
        const int lim = min(base + SCHUNK, N_EDGES);
        for (int i = base + tid; i < lim; i += 256) {
            int d = __builtin_nontemporal_load(&dst[i]);
            if (d / NPS == s) {
                int sv = __builtin_nontemporal_load(&src[i]);
                int pos = atomicAdd(&deg[d], 1);
                if (pos < MAXDEG) col64[(d << 6) + pos] = (unsigned short)sv;
            }
        }
        return;
    }
    if (blk < SCAT_GRID + CONV_GRID) {
        // pack X fp32 [50000][261] -> Xbf bf16 [NPAD][288] (zero-padded)
        int t = (blk - SCAT_GRID) * 256 + tid;   // short8 group index
        int node = t / (KPAD0 / 8);              // 36 groups per row
        int k8 = (t - node * (KPAD0 / 8)) * 8;
        short8 v8;
        if (node < N_NODES) {
            #pragma unroll
            for (int j = 0; j < 8; ++j) {
                int k = k8 + j;
                float val = (k < 261) ? __builtin_nontemporal_load(&X[(size_t)node * 261 + k]) : 0.0f;
                v8[j] = (short)f2bf(val);
            }
        } else {
            #pragma unroll
            for (int j = 0; j < 8; ++j) v8[j] = 0;
        }
        *(short8*)&Xbf[(size_t)node * KPAD0 + k8] = v8;
        return;
    }
    // weight transpose to bf16
    int idx = (blk - SCAT_GRID - CONV_GRID) * 256 + tid;
    const int n0 = 128 * KPAD0;
    if (idx < n0) {
        int j = idx / KPAD0, k = idx - j * KPAD0;
        float v = 0.0f;
        if (k < 261) v = (j < 64) ? Wl0[k * 64 + j] : Wr0[k * 64 + (j - 64)];
        Bt0[idx] = f2bf(v);
    } else if (idx < PREPW_TOT) {
        int r = idx - n0;
        int l = r >> 13;
        int rr = r & 8191;
        int j = rr >> 6, k = rr & 63;
        float v = (j < 64) ? Wl[l * 4096 + k * 64 + j] : Wr[l * 4096 + k * 64 + (j - 64)];
        BtR[r] = f2bf(v);
    }
}

// ---------------- proj GEMM: [U|V] = Xbf @ [Wl0|Wr0] ----------------
// Block = (64-row tile, 64-col half). B half (64x288) staged once into padded
// LDS, one barrier, then a barrier-free 9-chunk K-loop: direct streaming
// short8 A-loads from Xbf + LDS B + MFMA.

__global__ __launch_bounds__(256) void k_gemm0(
        const unsigned short* __restrict__ Xbf, const unsigned short* __restrict__ Bt0,
        unsigned short* __restrict__ U, float* __restrict__ V) {
    __shared__ __align__(16) unsigned short sB[64 * 296];   // 296 = 288 + 8 pad
    const int tid = threadIdx.x;
    const int lane = tid & 63, wid = tid >> 6;
    const int l16 = lane & 15, quad = lane >> 4;
    const int ch = blockIdx.x & 1;          // 0: U cols 0-63, 1: V cols 64-127
    const int m0 = (blockIdx.x >> 1) * 64;
    #pragma unroll
    for (int k = 0; k < 9; ++k) {           // 64 rows * 36 groups = 2304
        int g = k * 256 + tid;
        int row = g / 36;
        int part = (g - row * 36) * 8;
        *(short8*)&sB[row * 296 + part] =
            *(const short8*)&Bt0[(size_t)(ch * 64 + row) * KPAD0 + part];
    }
    f32x4 acc[4];
    #pragma unroll
    for (int j = 0; j < 4; ++j) { acc[j][0] = 0.f; acc[j][1] = 0.f; acc[j][2] = 0.f; acc[j][3] = 0.f; }
    const unsigned short* xr = Xbf + (size_t)(m0 + wid * 16 + l16) * KPAD0 + quad * 8;
    __syncthreads();
    for (int kc = 0; kc < KPAD0; kc += 32) {
        short8 af = *(const short8*)(xr + kc);
        #pragma unroll
        for (int j = 0; j < 4; ++j) {
            short8 bfv = *(const short8*)&sB[(j * 16 + l16) * 296 + kc + quad * 8];
            acc[j] = __builtin_amdgcn_mfma_f32_16x16x32_bf16(af, bfv, acc[j], 0, 0, 0);
        }
    }
    const int rbase = m0 + wid * 16 + quad * 4;
    if (ch == 0) {
        #pragma unroll
        for (int j = 0; j < 4; ++j)
            #pragma unroll
            for (int r = 0; r < 4; ++r)
                U[(size_t)(rbase + r) * 64 + j * 16 + l16] = f2bf(acc[j][r]);
    } else {
        #pragma unroll
        for (int j = 0; j < 4; ++j)
            #pragma unroll
            for (int r = 0; r < 4; ++r)
                V[(size_t)(rbase + r) * 64 + j * 16 + l16] = acc[j][r];
    }
}

// ---------------- fused layer: aggln(layer i) + mgemm(layer i+1) ----------------
// 32 nodes per block. __launch_bounds__(256,6): cap VGPR at ~85 so 6 blocks/CU
// co-reside (round-8 counters showed the 96-VGPR variant capped at 4 blocks/CU
// = half the TLP the latency-bound gather needs; grid is 6.1 blocks/CU).
// sB staged at kernel top (hidden under gather); LN output parked in LDS as
// the GEMM A-tile. ONE barrier, then zero-barrier K=64 MFMA.
// Last layer (pool_part != null): wave-reduce + atomicAdd into partial.

__global__ __launch_bounds__(256, 6) void k_layer(
        const unsigned short* __restrict__ U_in, const float* __restrict__ V_in,
        unsigned short* __restrict__ h,            // in-place: residual in, LN out
        const int* __restrict__ deg, const unsigned short* __restrict__ col64,
        const float* __restrict__ bias, const float* __restrict__ gam,
        const float* __restrict__ bet,
        const unsigned short* __restrict__ Bt_next,
        unsigned short* __restrict__ U_out, float* __restrict__ V_out,
        const int* __restrict__ batch, float* __restrict__ pool_part,
        int residual, int have_gemm) {
    __shared__ __align__(16) unsigned short sA[2 * 32 * 32];  // [chunk][row][32k]
    __shared__ __align__(16) unsigned short sB[128 * 72];     // 72 = 64 + 8 pad
    const int tid = threadIdx.x;
    const int lane = tid & 63, wid = tid >> 6;
    const int sub = lane >> 3, hl = lane & 7;
    const int base = lane & 56;
    const int m0 = blockIdx.x * 32;
    const uint4* __restrict__ Up = (const uint4*)U_in;

    if (have_gemm) {
        #pragma unroll
        for (int k = 0; k < 4; ++k) {       // 128 rows * 8 groups = 1024
            int g = k * 256 + tid;
            int row = g >> 3, part = (g & 7) * 8;
            *(short8*)&sB[row * 72 + part] = *(const short8*)&Bt_next[(size_t)row * 64 + part];
        }
    }

    const int nl = wid * 8 + sub;          // 0..31: node-in-tile
    const int node = m0 + nl;
    const bool valid = (node < N_NODES);
    const int nd = valid ? node : 0;
    const int dg = valid ? deg[nd] : 0;
    const int cnt = min(dg, MAXDEG);
    uint4 cv = make_uint4(0u, 0u, 0u, 0u);
    if (valid) cv = *(const uint4*)&col64[((size_t)nd << 6) + hl * 8];
    float s0 = 0.f, s1 = 0.f, s2 = 0.f, s3 = 0.f, s4 = 0.f, s5 = 0.f, s6 = 0.f, s7 = 0.f;
    for (int b = 0; b * 8 < cnt; b += 2) {
        #pragma unroll
        for (int hh = 0; hh < 2; ++hh) {
            const int sl = base + b + hh;
            unsigned int p0 = (unsigned int)__shfl((int)cv.x, sl);
            unsigned int p1 = (unsigned int)__shfl((int)cv.y, sl);
            unsigned int p2 = (unsigned int)__shfl((int)cv.z, sl);
            unsigned int p3 = (unsigned int)__shfl((int)cv.w, sl);
            const int eb = (b + hh) * 8;
            int c[8];
            c[0] = (int)(p0 & 0xffffu); c[1] = (int)(p0 >> 16);
            c[2] = (int)(p1 & 0xffffu); c[3] = (int)(p1 >> 16);
            c[4] = (int)(p2 & 0xffffu); c[5] = (int)(p2 >> 16);
            c[6] = (int)(p3 & 0xffffu); c[7] = (int)(p3 >> 16);
            #pragma unroll
            for (int i = 0; i < 8; ++i) {
                uint4 u = (eb + i < cnt) ? Up[(size_t)c[i] * 8 + hl] : make_uint4(0u, 0u, 0u, 0u);
                s0 += bf_lo(u.x); s1 += bf_hi(u.x);
                s2 += bf_lo(u.y); s3 += bf_hi(u.y);
                s4 += bf_lo(u.z); s5 += bf_hi(u.z);
                s6 += bf_lo(u.w); s7 += bf_hi(u.w);
            }
        }
    }
    const float id = 1.0f / fmaxf((float)dg, 1.0f);
    const float4 b0 = *(const float4*)&bias[8 * hl];
    const float4 b1 = *(const float4*)&bias[8 * hl + 4];
    float4 v0 = make_float4(0.f, 0.f, 0.f, 0.f), v1 = v0;
    if (valid) {
        v0 = *(const float4*)&V_in[(size_t)nd * 64 + 8 * hl];
        v1 = *(const float4*)&V_in[(size_t)nd * 64 + 8 * hl + 4];
    }
    float f0 = gelu_f(s0 * id + b0.x + v0.x);
    float f1 = gelu_f(s1 * id + b0.y + v0.y);
    float f2 = gelu_f(s2 * id + b0.z + v0.z);
    float f3 = gelu_f(s3 * id + b0.w + v0.w);
    float f4 = gelu_f(s4 * id + b1.x + v1.x);
    float f5 = gelu_f(s5 * id + b1.y + v1.y);
    float f6 = gelu_f(s6 * id + b1.z + v1.z);
    float f7 = gelu_f(s7 * id + b1.w + v1.w);
    float mu = group_sum8(((f0 + f1) + (f2 + f3)) + ((f4 + f5) + (f6 + f7))) * 0.015625f;
    float d0 = f0 - mu, d1 = f1 - mu, d2 = f2 - mu, d3 = f3 - mu;
    float d4 = f4 - mu, d5 = f5 - mu, d6 = f6 - mu, d7 = f7 - mu;
    float var = group_sum8(((d0 * d0 + d1 * d1) + (d2 * d2 + d3 * d3)) +
                           ((d4 * d4 + d5 * d5) + (d6 * d6 + d7 * d7))) * 0.015625f;
    float rs = rsqrtf(var + 1e-5f);
    const float4 g0v = *(const float4*)&gam[8 * hl];
    const float4 g1v = *(const float4*)&gam[8 * hl + 4];
    const float4 e0v = *(const float4*)&bet[8 * hl];
    const float4 e1v = *(const float4*)&bet[8 * hl + 4];
    f0 = d0 * rs * g0v.x + e0v.x;
    f1 = d1 * rs * g0v.y + e0v.y;
    f2 = d2 * rs * g0v.z + e0v.z;
    f3 = d3 * rs * g0v.w + e0v.w;
    f4 = d4 * rs * g1v.x + e1v.x;
    f5 = d5 * rs * g1v.y + e1v.y;
    f6 = d6 * rs * g1v.z + e1v.z;
    f7 = d7 * rs * g1v.w + e1v.w;
    if (residual && valid) {
        uint4 hu = ((const uint4*)h)[(size_t)nd * 8 + hl];
        f0 += bf_lo(hu.x); f1 += bf_hi(hu.x);
        f2 += bf_lo(hu.y); f3 += bf_hi(hu.y);
        f4 += bf_lo(hu.z); f5 += bf_hi(hu.z);
        f6 += bf_lo(hu.w); f7 += bf_hi(hu.w);
    }

    if (pool_part) {
        // ---- last layer: fold graph pooling, skip h write ----
        const int myg = valid ? batch[nd] : -1;
        const int i_lo = (m0 < N_NODES) ? m0 : (N_NODES - 1);
        const int i_hi = (m0 + 31 < N_NODES) ? (m0 + 31) : (N_NODES - 1);
        const int g_lo = batch[i_lo];
        const int g_hi = batch[i_hi];
        const int split = blockIdx.x & (PSPLIT - 1);
        for (int g = g_lo; g <= g_hi; ++g) {
            const bool mine = (myg == g);
            float p0 = mine ? f0 : 0.f, p1 = mine ? f1 : 0.f;
            float p2 = mine ? f2 : 0.f, p3 = mine ? f3 : 0.f;
            float p4 = mine ? f4 : 0.f, p5 = mine ? f5 : 0.f;
            float p6 = mine ? f6 : 0.f, p7 = mine ? f7 : 0.f;
            p0 += __shfl_xor(p0, 8);  p1 += __shfl_xor(p1, 8);
            p2 += __shfl_xor(p2, 8);  p3 += __shfl_xor(p3, 8);
            p4 += __shfl_xor(p4, 8);  p5 += __shfl_xor(p5, 8);
            p6 += __shfl_xor(p6, 8);  p7 += __shfl_xor(p7, 8);
            p0 += __shfl_xor(p0, 16); p1 += __shfl_xor(p1, 16);
            p2 += __shfl_xor(p2, 16); p3 += __shfl_xor(p3, 16);
            p4 += __shfl_xor(p4, 16); p5 += __shfl_xor(p5, 16);
            p6 += __shfl_xor(p6, 16); p7 += __shfl_xor(p7, 16);
            p0 += __shfl_xor(p0, 32); p1 += __shfl_xor(p1, 32);
            p2 += __shfl_xor(p2, 32); p3 += __shfl_xor(p3, 32);
            p4 += __shfl_xor(p4, 32); p5 += __shfl_xor(p5, 32);
            p6 += __shfl_xor(p6, 32); p7 += __shfl_xor(p7, 32);
            if (sub == 0) {
                float* dp = &pool_part[((size_t)g * PSPLIT + split) * 64 + 8 * hl];
                atomicAdd(dp + 0, p0); atomicAdd(dp + 1, p1);
                atomicAdd(dp + 2, p2); atomicAdd(dp + 3, p3);
                atomicAdd(dp + 4, p4); atomicAdd(dp + 5, p5);
                atomicAdd(dp + 6, p6); atomicAdd(dp + 7, p7);
            }
        }
        return;
    }

    uint4 outw;
    outw.x = (unsigned int)f2bf(f0) | ((unsigned int)f2bf(f1) << 16);
    outw.y = (unsigned int)f2bf(f2) | ((unsigned int)f2bf(f3) << 16);
    outw.z = (unsigned int)f2bf(f4) | ((unsigned int)f2bf(f5) << 16);
    outw.w = (unsigned int)f2bf(f6) | ((unsigned int)f2bf(f7) << 16);
    if (valid) ((uint4*)h)[(size_t)nd * 8 + hl] = outw;
    // park LN output in LDS as next-GEMM A-tile: chunk=hl>>2, k-offset=(hl&3)*8
    *(uint4*)&sA[(((hl >> 2) * 32 + nl) << 5) + (hl & 3) * 8] = outw;

    if (!have_gemm) return;
    __syncthreads();   // the ONLY barrier: covers sA park + sB staging

    // ---- GEMM: [U_out | V_out](rows m0..m0+31) = sA @ sB, K=64 ----
    const int l16 = lane & 15, quad = lane >> 4;
    const int wrow = wid & 1, colh = wid >> 1;
    f32x4 acc[4];
    #pragma unroll
    for (int j = 0; j < 4; ++j) { acc[j][0] = 0.f; acc[j][1] = 0.f; acc[j][2] = 0.f; acc[j][3] = 0.f; }
    #pragma unroll
    for (int kc = 0; kc < 64; kc += 32) {
        short8 af = *(const short8*)&sA[(((kc >> 5) * 32 + wrow * 16 + l16) << 5) + quad * 8];
        #pragma unroll
        for (int j = 0; j < 4; ++j) {
            short8 bfv = *(const short8*)&sB[(colh * 64 + j * 16 + l16) * 72 + kc + quad * 8];
            acc[j] = __builtin_amdgcn_mfma_f32_16x16x32_bf16(af, bfv, acc[j], 0, 0, 0);
        }
    }
    const int rbase = m0 + wrow * 16 + quad * 4;
    if (colh == 0) {
        #pragma unroll
        for (int j = 0; j < 4; ++j)
            #pragma unroll
            for (int r = 0; r < 4; ++r)
                U_out[(size_t)(rbase + r) * 64 + j * 16 + l16] = f2bf(acc[j][r]);
    } else {
        #pragma unroll
        for (int j = 0; j < 4; ++j)
            #pragma unroll
            for (int r = 0; r < 4; ++r)
                V_out[(size_t)(rbase + r) * 64 + j * 16 + l16] = acc[j][r];
    }
}

// ---------------- MLP head (folds pool stage 2) ----------------

__global__ __launch_bounds__(1024) void k_head(const float* __restrict__ partial,
                                               const float* __restrict__ M0, const float* __restrict__ mb0,
                                               const float* __restrict__ mg0, const float* __restrict__ mbeta0,
                                               const float* __restrict__ M, const float* __restrict__ mb,
                                               const float* __restrict__ mg, const float* __restrict__ mbeta,
                                               const float* __restrict__ Wf, const float* __restrict__ bf,
                                               float* __restrict__ out) {
    __shared__ float sP[64 * 64];
    __shared__ float sA[64 * 33];
    __shared__ float sB[64 * 33];
    const int tx = threadIdx.x, ty = threadIdx.y;
    const int tid = ty * 32 + tx;
    for (int i = tid; i < 64 * 64; i += 1024) {
        int g = i >> 6, f = i & 63;
        float s = 0.0f;
        #pragma unroll
        for (int s2 = 0; s2 < PSPLIT; ++s2) s += partial[(size_t)(g * PSPLIT + s2) * 64 + f];
        sP[i] = s;
    }
    __syncthreads();
    #pragma unroll
    for (int rr = 0; rr < 2; ++rr) {
        int r = ty + rr * 32;
        float a = mb0[tx];
        for (int k = 0; k < 64; ++k) a += sP[r * 64 + k] * M0[k * 32 + tx];
        a = gelu_f(a);
        float mu = half_sum32(a) * (1.0f / 32.0f);
        float d = a - mu;
        float var = half_sum32(d * d) * (1.0f / 32.0f);
        a = d * rsqrtf(var + 1e-5f) * mg0[tx] + mbeta0[tx];
        sA[r * 33 + tx] = a;
    }
    __syncthreads();
    float* cur = sA;
    float* nxt = sB;
    for (int L = 0; L < 3; ++L) {
        const float* Mi = M + L * 32 * 32;
        const float* mbi = mb + L * 32;
        const float* mgi = mg + L * 32;
        const float* mbetai = mbeta + L * 32;
        #pragma unroll
        for (int rr = 0; rr < 2; ++rr) {
            int r = ty + rr * 32;
            float a = mbi[tx];
            for (int k = 0; k < 32; ++k) a += cur[r * 33 + k] * Mi[k * 32 + tx];
            a = gelu_f(a);
            float mu = half_sum32(a) * (1.0f / 32.0f);
            float d = a - mu;
            float var = half_sum32(d * d) * (1.0f / 32.0f);
            a = d * rsqrtf(var + 1e-5f) * mgi[tx] + mbetai[tx] + cur[r * 33 + tx];
            nxt[r * 33 + tx] = a;
        }
        __syncthreads();
        float* t = cur; cur = nxt; nxt = t;
    }
    #pragma unroll
    for (int rr = 0; rr < 2; ++rr) {
        int r = ty + rr * 32;
        float p = cur[r * 33 + tx] * Wf[tx];
        p = half_sum32(p);
        if (tx == 0) out[r] = p + bf[0];
    }
}

// ---------------- host launcher ----------------

extern "C" void kernel_launch(void* const* d_in, const int* in_sizes, int n_in,
                              void* d_out, int out_size, void* d_ws, size_t ws_size,
                              hipStream_t stream) {
    const int N = N_NODES;
    const int E = N_EDGES;

    const float* x    = (const float*)d_in[0];
    const int* eidx   = (const int*)d_in[1];
    const int* batch  = (const int*)d_in[2];
    const float* Wl0  = (const float*)d_in[3];
    const float* bl0  = (const float*)d_in[4];
    const float* Wr0  = (const float*)d_in[5];
    const float* g0   = (const float*)d_in[6];
    const float* bet0 = (const float*)d_in[7];
    const float* Wl   = (const float*)d_in[8];
    const float* bl   = (const float*)d_in[9];
    const float* Wr   = (const float*)d_in[10];
    const float* gR   = (const float*)d_in[11];
    const float* betR = (const float*)d_in[12];
    const float* M0   = (const float*)d_in[13];
    const float* mb0  = (const float*)d_in[14];
    const float* mg0  = (const float*)d_in[15];
    const float* mbe0 = (const float*)d_in[16];
    const float* M    = (const float*)d_in[17];
    const float* mb   = (const float*)d_in[18];
    const float* mg   = (const float*)d_in[19];
    const float* mbe  = (const float*)d_in[20];
    const float* Wf   = (const float*)d_in[21];
    const float* bf   = (const float*)d_in[22];

    const int* src = eidx;
    const int* dst = eidx + E;

    char* p = (char*)d_ws;
    auto alloc = [&](size_t bytes) -> void* {
        void* q = (void*)p;
        p += (bytes + 255) & ~(size_t)255;
        return q;
    };
    // deg + partial first and contiguous: one memset zeroes both
    int*   deg     = (int*)alloc((size_t)N * 4);
    float* partial = (float*)alloc((size_t)NUM_GRAPHS * PSPLIT * 64 * 4);
    unsigned short* col64 = (unsigned short*)alloc((size_t)N * MAXDEG * 2);
    unsigned short* Bt0 = (unsigned short*)alloc((size_t)128 * KPAD0 * 2);
    unsigned short* BtR = (unsigned short*)alloc((size_t)6 * 128 * 64 * 2);
    unsigned short* Xbf = (unsigned short*)alloc((size_t)NPAD * KPAD0 * 2);
    unsigned short* Ua  = (unsigned short*)alloc((size_t)NPAD * 64 * 2);
    unsigned short* Ub  = (unsigned short*)alloc((size_t)NPAD * 64 * 2);
    float* Va   = (float*)alloc((size_t)NPAD * 64 * 4);
    float* Vb   = (float*)alloc((size_t)NPAD * 64 * 4);
    unsigned short* hbuf = (unsigned short*)alloc((size_t)NPAD * 64 * 2);

    // zero deg + partial (contiguous span)
    size_t zspan = (size_t)((char*)col64 - (char*)deg);
    hipMemsetAsync(deg, 0, zspan, stream);

    // fused front: scatter | X->bf16 pack | weight transpose
    k_front<<<FRONT_GRID, 256, 0, stream>>>(
        src, dst, deg, col64, x, Xbf, Wl0, Wr0, Wl, Wr, Bt0, BtR);

    // projection GEMM: [U|V] = Xbf @ [Wl0|Wr0]
    k_gemm0<<<G0_GRID, 256, 0, stream>>>(Xbf, Bt0, Ua, Va);

    // 7 fused layer kernels: aggln(i) + gemm(i+1). U/V ping-pong; h in-place.
    // Last layer folds graph pooling (atomic partial sums).
    unsigned short* Uin = Ua;  float* Vin = Va;
    unsigned short* Uout = Ub; float* Vout = Vb;
    for (int i = 0; i < 7; ++i) {
        const float* bias = (i == 0) ? bl0  : bl  + (size_t)(i - 1) * 64;
        const float* gam  = (i == 0) ? g0   : gR  + (size_t)(i - 1) * 64;
        const float* bet  = (i == 0) ? bet0 : betR + (size_t)(i - 1) * 64;
        const int have_gemm = (i < 6);
        float* pool_part = (i == 6) ? partial : nullptr;
        k_layer<<<LAYER_GRID, 256, 0, stream>>>(
            Uin, Vin, hbuf, deg, col64, bias, gam, bet,
            have_gemm ? (BtR + (size_t)i * 128 * 64) : BtR,
            Uout, Vout, batch, pool_part, (i > 0) ? 1 : 0, have_gemm);
        unsigned short* tu = Uin; Uin = Uout; Uout = tu;
        float* tv = Vin; Vin = Vout; Vout = tv;
    }

    k_head<<<1, dim3(32, 32), 0, stream>>>(partial, M0, mb0, mg0, mbe0, M, mb, mg, mbe, Wf, bf, (float*)d_out);
}

// Round 10
// 377.800 us; speedup vs baseline: 2.0345x; 1.1580x over previous
//
#include <hip/hip_runtime.h>
#include <hip/hip_bf16.h>
#include <math.h>

#define N_NODES 50000
#define N_EDGES 800000
#define NUM_GRAPHS 64
#define NPAD 50048          // multiple of 64
#define KPAD0 288           // 261 padded to multiple of 32
#define PSPLIT 16
#define MAXDEG 64           // Poisson(16): P(deg>64) ~ 1e-20

#define G0_GRID    (NPAD / 32)                  // 1564: (row-tile, col-half) pairs
#define LAYER_GRID (NPAD / 32)                  // 1564
#define PREPW_TOT  (128 * KPAD0 + 6 * 128 * 64) // 86016
#define PREPW_GRID ((PREPW_TOT + 255) / 256)    // 336
#define CONV_GRID  (NPAD * (KPAD0 / 8) / 256)   // 7038: X->bf16 packing

// XCD-sliced scatter: slice s handles dst in [s*NPS, (s+1)*NPS)
#define SLICES 8
#define NPS 6250
#define SCHUNK 2048
#define SCHUNKS ((N_EDGES + SCHUNK - 1) / SCHUNK)   // 391
#define SCAT_GRID (SCHUNKS * SLICES)                // 3128
#define FRONT_GRID (SCAT_GRID + CONV_GRID + PREPW_GRID)  // 10502

typedef __attribute__((ext_vector_type(8))) short short8;
typedef __attribute__((ext_vector_type(4))) float f32x4;

__device__ __forceinline__ float gelu_f(float v) {
    return 0.5f * v * (1.0f + erff(v * 0.70710678118654752440f));
}

__device__ __forceinline__ float half_sum32(float v) {
    v += __shfl_xor(v, 1); v += __shfl_xor(v, 2); v += __shfl_xor(v, 4);
    v += __shfl_xor(v, 8); v += __shfl_xor(v, 16);
    return v;
}

__device__ __forceinline__ float group_sum8(float v) {
    v += __shfl_xor(v, 1); v += __shfl_xor(v, 2); v += __shfl_xor(v, 4);
    return v;
}

__device__ __forceinline__ unsigned short f2bf(float f) {
    unsigned int u = __float_as_uint(f);
    unsigned int r = (u + 0x7fffu + ((u >> 16) & 1u)) >> 16;
    return (unsigned short)r;
}

__device__ __forceinline__ float bf_lo(unsigned int u) {
    return __uint_as_float(u << 16);
}
__device__ __forceinline__ float bf_hi(unsigned int u) {
    return __uint_as_float(u & 0xffff0000u);
}

// ---------------- fused front: scatter | X->bf16 conv | weight transpose ----------------
// Scatter blocks FIRST (latency-bound, span the launch); conv (streaming) and
// weight blocks fill the memory pipes behind them. NO nontemporal loads: the
// 8-pass dst re-read depends on L2/L3 reuse (round-9: nt cost +15 MB, +12 us).
// deg zeroed by preceding hipMemsetAsync. No LDS anywhere -> full occupancy.

__global__ __launch_bounds__(256) void k_front(
        const int* __restrict__ src, const int* __restrict__ dst,
        int* __restrict__ deg, unsigned short* __restrict__ col64,
        const float* __restrict__ X, unsigned short* __restrict__ Xbf,
        const float* __restrict__ Wl0, const float* __restrict__ Wr0,
        const float* __restrict__ Wl, const float* __restrict__ Wr,
        unsigned short* __restrict__ Bt0, unsigned short* __restrict__ BtR) {
    const int blk = blockIdx.x;
    const int tid = threadIdx.x;
    if (blk < SCAT_GRID) {
        // XCD-sliced scatter: slice = blk & 7 (round-robin blockIdx -> XCD
        // keeps each slice's col64/deg window resident in one XCD's L2)
        const int s = blk & (SLICES - 1);
        const int c = blk >> 3;
        const int base = c * SCHUNK;
        const int lim = min(base + SCHUNK, N_EDGES);
        for (int i = base + tid; i < lim; i += 256) {
            int d = dst[i];
            if (d / NPS == s) {
                int sv = src[i];
                int pos = atomicAdd(&deg[d], 1);
                if (pos < MAXDEG) col64[(d << 6) + pos] = (unsigned short)sv;
            }
        }
        return;
    }
    if (blk < SCAT_GRID + CONV_GRID) {
        // pack X fp32 [50000][261] -> Xbf bf16 [NPAD][288] (zero-padded)
        int t = (blk - SCAT_GRID) * 256 + tid;   // short8 group index
        int node = t / (KPAD0 / 8);              // 36 groups per row
        int k8 = (t - node * (KPAD0 / 8)) * 8;
        short8 v8;
        if (node < N_NODES) {
            #pragma unroll
            for (int j = 0; j < 8; ++j) {
                int k = k8 + j;
                float val = (k < 261) ? X[(size_t)node * 261 + k] : 0.0f;
                v8[j] = (short)f2bf(val);
            }
        } else {
            #pragma unroll
            for (int j = 0; j < 8; ++j) v8[j] = 0;
        }
        *(short8*)&Xbf[(size_t)node * KPAD0 + k8] = v8;
        return;
    }
    // weight transpose to bf16
    int idx = (blk - SCAT_GRID - CONV_GRID) * 256 + tid;
    const int n0 = 128 * KPAD0;
    if (idx < n0) {
        int j = idx / KPAD0, k = idx - j * KPAD0;
        float v = 0.0f;
        if (k < 261) v = (j < 64) ? Wl0[k * 64 + j] : Wr0[k * 64 + (j - 64)];
        Bt0[idx] = f2bf(v);
    } else if (idx < PREPW_TOT) {
        int r = idx - n0;
        int l = r >> 13;
        int rr = r & 8191;
        int j = rr >> 6, k = rr & 63;
        float v = (j < 64) ? Wl[l * 4096 + k * 64 + j] : Wr[l * 4096 + k * 64 + (j - 64)];
        BtR[r] = f2bf(v);
    }
}

// ---------------- proj GEMM: [U|V] = Xbf @ [Wl0|Wr0] ----------------
// Block = (64-row tile, 64-col half). B half (64x288) staged once into padded
// LDS, one barrier, then a barrier-free 9-chunk K-loop: direct streaming
// short8 A-loads from Xbf + LDS B + MFMA.

__global__ __launch_bounds__(256) void k_gemm0(
        const unsigned short* __restrict__ Xbf, const unsigned short* __restrict__ Bt0,
        unsigned short* __restrict__ U, float* __restrict__ V) {
    __shared__ __align__(16) unsigned short sB[64 * 296];   // 296 = 288 + 8 pad
    const int tid = threadIdx.x;
    const int lane = tid & 63, wid = tid >> 6;
    const int l16 = lane & 15, quad = lane >> 4;
    const int ch = blockIdx.x & 1;          // 0: U cols 0-63, 1: V cols 64-127
    const int m0 = (blockIdx.x >> 1) * 64;
    #pragma unroll
    for (int k = 0; k < 9; ++k) {           // 64 rows * 36 groups = 2304
        int g = k * 256 + tid;
        int row = g / 36;
        int part = (g - row * 36) * 8;
        *(short8*)&sB[row * 296 + part] =
            *(const short8*)&Bt0[(size_t)(ch * 64 + row) * KPAD0 + part];
    }
    f32x4 acc[4];
    #pragma unroll
    for (int j = 0; j < 4; ++j) { acc[j][0] = 0.f; acc[j][1] = 0.f; acc[j][2] = 0.f; acc[j][3] = 0.f; }
    const unsigned short* xr = Xbf + (size_t)(m0 + wid * 16 + l16) * KPAD0 + quad * 8;
    __syncthreads();
    for (int kc = 0; kc < KPAD0; kc += 32) {
        short8 af = *(const short8*)(xr + kc);
        #pragma unroll
        for (int j = 0; j < 4; ++j) {
            short8 bfv = *(const short8*)&sB[(j * 16 + l16) * 296 + kc + quad * 8];
            acc[j] = __builtin_amdgcn_mfma_f32_16x16x32_bf16(af, bfv, acc[j], 0, 0, 0);
        }
    }
    const int rbase = m0 + wid * 16 + quad * 4;
    if (ch == 0) {
        #pragma unroll
        for (int j = 0; j < 4; ++j)
            #pragma unroll
            for (int r = 0; r < 4; ++r)
                U[(size_t)(rbase + r) * 64 + j * 16 + l16] = f2bf(acc[j][r]);
    } else {
        #pragma unroll
        for (int j = 0; j < 4; ++j)
            #pragma unroll
            for (int r = 0; r < 4; ++r)
                V[(size_t)(rbase + r) * 64 + j * 16 + l16] = acc[j][r];
    }
}

// ---------------- fused layer: aggln(layer i) + mgemm(layer i+1) ----------------
// ROUND-2 VARIANT (best measured: 375.4 us total): 32 nodes per block,
// __launch_bounds__(256,4), sB staged INSIDE the K-loop per 32-k chunk.
// Cross-round attribution (R2->R4) showed this variant ~6 us/layer faster
// than top-staged-sB/one-barrier. Pool fold added for the last layer.

__global__ __launch_bounds__(256, 4) void k_layer(
        const unsigned short* __restrict__ U_in, const float* __restrict__ V_in,
        unsigned short* __restrict__ h,            // in-place: residual in, LN out
        const int* __restrict__ deg, const unsigned short* __restrict__ col64,
        const float* __restrict__ bias, const float* __restrict__ gam,
        const float* __restrict__ bet,
        const unsigned short* __restrict__ Bt_next,
        unsigned short* __restrict__ U_out, float* __restrict__ V_out,
        const int* __restrict__ batch, float* __restrict__ pool_part,
        int residual, int have_gemm) {
    __shared__ __align__(16) unsigned short sA[2 * 32 * 32];  // [chunk][row][32k]
    __shared__ __align__(16) unsigned short sB[128 * 32];
    const int tid = threadIdx.x;
    const int lane = tid & 63, wid = tid >> 6;
    const int sub = lane >> 3, hl = lane & 7;
    const int base = lane & 56;
    const int m0 = blockIdx.x * 32;
    const uint4* __restrict__ Up = (const uint4*)U_in;

    const int nl = wid * 8 + sub;          // 0..31: node-in-tile
    const int node = m0 + nl;
    const bool valid = (node < N_NODES);
    const int nd = valid ? node : 0;
    const int dg = valid ? deg[nd] : 0;
    const int cnt = min(dg, MAXDEG);
    uint4 cv = make_uint4(0u, 0u, 0u, 0u);
    if (valid) cv = *(const uint4*)&col64[((size_t)nd << 6) + hl * 8];
    float s0 = 0.f, s1 = 0.f, s2 = 0.f, s3 = 0.f, s4 = 0.f, s5 = 0.f, s6 = 0.f, s7 = 0.f;
    for (int b = 0; b * 8 < cnt; b += 2) {
        #pragma unroll
        for (int hh = 0; hh < 2; ++hh) {
            const int sl = base + b + hh;
            unsigned int p0 = (unsigned int)__shfl((int)cv.x, sl);
            unsigned int p1 = (unsigned int)__shfl((int)cv.y, sl);
            unsigned int p2 = (unsigned int)__shfl((int)cv.z, sl);
            unsigned int p3 = (unsigned int)__shfl((int)cv.w, sl);
            const int eb = (b + hh) * 8;
            int c[8];
            c[0] = (int)(p0 & 0xffffu); c[1] = (int)(p0 >> 16);
            c[2] = (int)(p1 & 0xffffu); c[3] = (int)(p1 >> 16);
            c[4] = (int)(p2 & 0xffffu); c[5] = (int)(p2 >> 16);
            c[6] = (int)(p3 & 0xffffu); c[7] = (int)(p3 >> 16);
            #pragma unroll
            for (int i = 0; i < 8; ++i) {
                uint4 u = (eb + i < cnt) ? Up[(size_t)c[i] * 8 + hl] : make_uint4(0u, 0u, 0u, 0u);
                s0 += bf_lo(u.x); s1 += bf_hi(u.x);
                s2 += bf_lo(u.y); s3 += bf_hi(u.y);
                s4 += bf_lo(u.z); s5 += bf_hi(u.z);
                s6 += bf_lo(u.w); s7 += bf_hi(u.w);
            }
        }
    }
    const float id = 1.0f / fmaxf((float)dg, 1.0f);
    const float4 b0 = *(const float4*)&bias[8 * hl];
    const float4 b1 = *(const float4*)&bias[8 * hl + 4];
    float4 v0 = make_float4(0.f, 0.f, 0.f, 0.f), v1 = v0;
    if (valid) {
        v0 = *(const float4*)&V_in[(size_t)nd * 64 + 8 * hl];
        v1 = *(const float4*)&V_in[(size_t)nd * 64 + 8 * hl + 4];
    }
    float f0 = gelu_f(s0 * id + b0.x + v0.x);
    float f1 = gelu_f(s1 * id + b0.y + v0.y);
    float f2 = gelu_f(s2 * id + b0.z + v0.z);
    float f3 = gelu_f(s3 * id + b0.w + v0.w);
    float f4 = gelu_f(s4 * id + b1.x + v1.x);
    float f5 = gelu_f(s5 * id + b1.y + v1.y);
    float f6 = gelu_f(s6 * id + b1.z + v1.z);
    float f7 = gelu_f(s7 * id + b1.w + v1.w);
    float mu = group_sum8(((f0 + f1) + (f2 + f3)) + ((f4 + f5) + (f6 + f7))) * 0.015625f;
    float d0 = f0 - mu, d1 = f1 - mu, d2 = f2 - mu, d3 = f3 - mu;
    float d4 = f4 - mu, d5 = f5 - mu, d6 = f6 - mu, d7 = f7 - mu;
    float var = group_sum8(((d0 * d0 + d1 * d1) + (d2 * d2 + d3 * d3)) +
                           ((d4 * d4 + d5 * d5) + (d6 * d6 + d7 * d7))) * 0.015625f;
    float rs = rsqrtf(var + 1e-5f);
    const float4 g0v = *(const float4*)&gam[8 * hl];
    const float4 g1v = *(const float4*)&gam[8 * hl + 4];
    const float4 e0v = *(const float4*)&bet[8 * hl];
    const float4 e1v = *(const float4*)&bet[8 * hl + 4];
    f0 = d0 * rs * g0v.x + e0v.x;
    f1 = d1 * rs * g0v.y + e0v.y;
    f2 = d2 * rs * g0v.z + e0v.z;
    f3 = d3 * rs * g0v.w + e0v.w;
    f4 = d4 * rs * g1v.x + e1v.x;
    f5 = d5 * rs * g1v.y + e1v.y;
    f6 = d6 * rs * g1v.z + e1v.z;
    f7 = d7 * rs * g1v.w + e1v.w;
    if (residual && valid) {
        uint4 hu = ((const uint4*)h)[(size_t)nd * 8 + hl];
        f0 += bf_lo(hu.x); f1 += bf_hi(hu.x);
        f2 += bf_lo(hu.y); f3 += bf_hi(hu.y);
        f4 += bf_lo(hu.z); f5 += bf_hi(hu.z);
        f6 += bf_lo(hu.w); f7 += bf_hi(hu.w);
    }

    if (pool_part) {
        // ---- last layer: fold graph pooling, skip h write ----
        const int myg = valid ? batch[nd] : -1;
        const int i_lo = (m0 < N_NODES) ? m0 : (N_NODES - 1);
        const int i_hi = (m0 + 31 < N_NODES) ? (m0 + 31) : (N_NODES - 1);
        const int g_lo = batch[i_lo];
        const int g_hi = batch[i_hi];
        const int split = blockIdx.x & (PSPLIT - 1);
        for (int g = g_lo; g <= g_hi; ++g) {
            const bool mine = (myg == g);
            float p0 = mine ? f0 : 0.f, p1 = mine ? f1 : 0.f;
            float p2 = mine ? f2 : 0.f, p3 = mine ? f3 : 0.f;
            float p4 = mine ? f4 : 0.f, p5 = mine ? f5 : 0.f;
            float p6 = mine ? f6 : 0.f, p7 = mine ? f7 : 0.f;
            p0 += __shfl_xor(p0, 8);  p1 += __shfl_xor(p1, 8);
            p2 += __shfl_xor(p2, 8);  p3 += __shfl_xor(p3, 8);
            p4 += __shfl_xor(p4, 8);  p5 += __shfl_xor(p5, 8);
            p6 += __shfl_xor(p6, 8);  p7 += __shfl_xor(p7, 8);
            p0 += __shfl_xor(p0, 16); p1 += __shfl_xor(p1, 16);
            p2 += __shfl_xor(p2, 16); p3 += __shfl_xor(p3, 16);
            p4 += __shfl_xor(p4, 16); p5 += __shfl_xor(p5, 16);
            p6 += __shfl_xor(p6, 16); p7 += __shfl_xor(p7, 16);
            p0 += __shfl_xor(p0, 32); p1 += __shfl_xor(p1, 32);
            p2 += __shfl_xor(p2, 32); p3 += __shfl_xor(p3, 32);
            p4 += __shfl_xor(p4, 32); p5 += __shfl_xor(p5, 32);
            p6 += __shfl_xor(p6, 32); p7 += __shfl_xor(p7, 32);
            if (sub == 0) {
                float* dp = &pool_part[((size_t)g * PSPLIT + split) * 64 + 8 * hl];
                atomicAdd(dp + 0, p0); atomicAdd(dp + 1, p1);
                atomicAdd(dp + 2, p2); atomicAdd(dp + 3, p3);
                atomicAdd(dp + 4, p4); atomicAdd(dp + 5, p5);
                atomicAdd(dp + 6, p6); atomicAdd(dp + 7, p7);
            }
        }
        return;
    }

    uint4 outw;
    outw.x = (unsigned int)f2bf(f0) | ((unsigned int)f2bf(f1) << 16);
    outw.y = (unsigned int)f2bf(f2) | ((unsigned int)f2bf(f3) << 16);
    outw.z = (unsigned int)f2bf(f4) | ((unsigned int)f2bf(f5) << 16);
    outw.w = (unsigned int)f2bf(f6) | ((unsigned int)f2bf(f7) << 16);
    if (valid) ((uint4*)h)[(size_t)nd * 8 + hl] = outw;
    // park LN output in LDS as next-GEMM A-tile: chunk=hl>>2, k-offset=(hl&3)*8
    *(uint4*)&sA[(((hl >> 2) * 32 + nl) << 5) + (hl & 3) * 8] = outw;

    if (!have_gemm) return;
    __syncthreads();

    // ---- GEMM: [U_out | V_out](rows m0..m0+31) = sA @ Bt_next, K=64 ----
    // R2 form: sB staged per 32-k chunk inside the loop.
    // 4 waves: wave w -> rows (w&1)*16..+15, col-half (w>>1)*64..+63
    const int l16 = lane & 15, quad = lane >> 4;
    const int wrow = wid & 1, colh = wid >> 1;
    f32x4 acc[4];
    #pragma unroll
    for (int j = 0; j < 4; ++j) { acc[j][0] = 0.f; acc[j][1] = 0.f; acc[j][2] = 0.f; acc[j][3] = 0.f; }
    for (int kc = 0; kc < 64; kc += 32) {
        if (kc) __syncthreads();
        #pragma unroll
        for (int q = 0; q < 2; ++q) {
            int flat = q * 256 + tid;
            int br = flat >> 2, bp = (flat & 3) << 3;
            *(int4*)&sB[br * 32 + bp] = *(const int4*)&Bt_next[(size_t)br * 64 + kc + bp];
        }
        __syncthreads();
        short8 af = *(const short8*)&sA[(((kc >> 5) * 32 + wrow * 16 + l16) << 5) + quad * 8];
        #pragma unroll
        for (int j = 0; j < 4; ++j) {
            short8 bfv = *(const short8*)&sB[(colh * 64 + j * 16 + l16) * 32 + quad * 8];
            acc[j] = __builtin_amdgcn_mfma_f32_16x16x32_bf16(af, bfv, acc[j], 0, 0, 0);
        }
    }
    const int rbase = m0 + wrow * 16 + quad * 4;
    if (colh == 0) {
        #pragma unroll
        for (int j = 0; j < 4; ++j)
            #pragma unroll
            for (int r = 0; r < 4; ++r)
                U_out[(size_t)(rbase + r) * 64 + j * 16 + l16] = f2bf(acc[j][r]);
    } else {
        #pragma unroll
        for (int j = 0; j < 4; ++j)
            #pragma unroll
            for (int r = 0; r < 4; ++r)
                V_out[(size_t)(rbase + r) * 64 + j * 16 + l16] = acc[j][r];
    }
}

// ---------------- MLP head (folds pool stage 2) ----------------

__global__ __launch_bounds__(1024) void k_head(const float* __restrict__ partial,
                                               const float* __restrict__ M0, const float* __restrict__ mb0,
                                               const float* __restrict__ mg0, const float* __restrict__ mbeta0,
                                               const float* __restrict__ M, const float* __restrict__ mb,
                                               const float* __restrict__ mg, const float* __restrict__ mbeta,
                                               const float* __restrict__ Wf, const float* __restrict__ bf,
                                               float* __restrict__ out) {
    __shared__ float sP[64 * 64];
    __shared__ float sA[64 * 33];
    __shared__ float sB[64 * 33];
    const int tx = threadIdx.x, ty = threadIdx.y;
    const int tid = ty * 32 + tx;
    for (int i = tid; i < 64 * 64; i += 1024) {
        int g = i >> 6, f = i & 63;
        float s = 0.0f;
        #pragma unroll
        for (int s2 = 0; s2 < PSPLIT; ++s2) s += partial[(size_t)(g * PSPLIT + s2) * 64 + f];
        sP[i] = s;
    }
    __syncthreads();
    #pragma unroll
    for (int rr = 0; rr < 2; ++rr) {
        int r = ty + rr * 32;
        float a = mb0[tx];
        for (int k = 0; k < 64; ++k) a += sP[r * 64 + k] * M0[k * 32 + tx];
        a = gelu_f(a);
        float mu = half_sum32(a) * (1.0f / 32.0f);
        float d = a - mu;
        float var = half_sum32(d * d) * (1.0f / 32.0f);
        a = d * rsqrtf(var + 1e-5f) * mg0[tx] + mbeta0[tx];
        sA[r * 33 + tx] = a;
    }
    __syncthreads();
    float* cur = sA;
    float* nxt = sB;
    for (int L = 0; L < 3; ++L) {
        const float* Mi = M + L * 32 * 32;
        const float* mbi = mb + L * 32;
        const float* mgi = mg + L * 32;
        const float* mbetai = mbeta + L * 32;
        #pragma unroll
        for (int rr = 0; rr < 2; ++rr) {
            int r = ty + rr * 32;
            float a = mbi[tx];
            for (int k = 0; k < 32; ++k) a += cur[r * 33 + k] * Mi[k * 32 + tx];
            a = gelu_f(a);
            float mu = half_sum32(a) * (1.0f / 32.0f);
            float d = a - mu;
            float var = half_sum32(d * d) * (1.0f / 32.0f);
            a = d * rsqrtf(var + 1e-5f) * mgi[tx] + mbetai[tx] + cur[r * 33 + tx];
            nxt[r * 33 + tx] = a;
        }
        __syncthreads();
        float* t = cur; cur = nxt; nxt = t;
    }
    #pragma unroll
    for (int rr = 0; rr < 2; ++rr) {
        int r = ty + rr * 32;
        float p = cur[r * 33 + tx] * Wf[tx];
        p = half_sum32(p);
        if (tx == 0) out[r] = p + bf[0];
    }
}

// ---------------- host launcher ----------------

extern "C" void kernel_launch(void* const* d_in, const int* in_sizes, int n_in,
                              void* d_out, int out_size, void* d_ws, size_t ws_size,
                              hipStream_t stream) {
    const int N = N_NODES;
    const int E = N_EDGES;

    const float* x    = (const float*)d_in[0];
    const int* eidx   = (const int*)d_in[1];
    const int* batch  = (const int*)d_in[2];
    const float* Wl0  = (const float*)d_in[3];
    const float* bl0  = (const float*)d_in[4];
    const float* Wr0  = (const float*)d_in[5];
    const float* g0   = (const float*)d_in[6];
    const float* bet0 = (const float*)d_in[7];
    const float* Wl   = (const float*)d_in[8];
    const float* bl   = (const float*)d_in[9];
    const float* Wr   = (const float*)d_in[10];
    const float* gR   = (const float*)d_in[11];
    const float* betR = (const float*)d_in[12];
    const float* M0   = (const float*)d_in[13];
    const float* mb0  = (const float*)d_in[14];
    const float* mg0  = (const float*)d_in[15];
    const float* mbe0 = (const float*)d_in[16];
    const float* M    = (const float*)d_in[17];
    const float* mb   = (const float*)d_in[18];
    const float* mg   = (const float*)d_in[19];
    const float* mbe  = (const float*)d_in[20];
    const float* Wf   = (const float*)d_in[21];
    const float* bf   = (const float*)d_in[22];

    const int* src = eidx;
    const int* dst = eidx + E;

    char* p = (char*)d_ws;
    auto alloc = [&](size_t bytes) -> void* {
        void* q = (void*)p;
        p += (bytes + 255) & ~(size_t)255;
        return q;
    };
    // deg + partial first and contiguous: one memset zeroes both
    int*   deg     = (int*)alloc((size_t)N * 4);
    float* partial = (float*)alloc((size_t)NUM_GRAPHS * PSPLIT * 64 * 4);
    unsigned short* col64 = (unsigned short*)alloc((size_t)N * MAXDEG * 2);
    unsigned short* Bt0 = (unsigned short*)alloc((size_t)128 * KPAD0 * 2);
    unsigned short* BtR = (unsigned short*)alloc((size_t)6 * 128 * 64 * 2);
    unsigned short* Xbf = (unsigned short*)alloc((size_t)NPAD * KPAD0 * 2);
    unsigned short* Ua  = (unsigned short*)alloc((size_t)NPAD * 64 * 2);
    unsigned short* Ub  = (unsigned short*)alloc((size_t)NPAD * 64 * 2);
    float* Va   = (float*)alloc((size_t)NPAD * 64 * 4);
    float* Vb   = (float*)alloc((size_t)NPAD * 64 * 4);
    unsigned short* hbuf = (unsigned short*)alloc((size_t)NPAD * 64 * 2);

    // zero deg + partial (contiguous span)
    size_t zspan = (size_t)((char*)col64 - (char*)deg);
    hipMemsetAsync(deg, 0, zspan, stream);

    // fused front: scatter | X->bf16 pack | weight transpose
    k_front<<<FRONT_GRID, 256, 0, stream>>>(
        src, dst, deg, col64, x, Xbf, Wl0, Wr0, Wl, Wr, Bt0, BtR);

    // projection GEMM: [U|V] = Xbf @ [Wl0|Wr0]
    k_gemm0<<<G0_GRID, 256, 0, stream>>>(Xbf, Bt0, Ua, Va);

    // 7 fused layer kernels: aggln(i) + gemm(i+1). U/V ping-pong; h in-place.
    // Last layer folds graph pooling (atomic partial sums).
    unsigned short* Uin = Ua;  float* Vin = Va;
    unsigned short* Uout = Ub; float* Vout = Vb;
    for (int i = 0; i < 7; ++i) {
        const float* bias = (i == 0) ? bl0  : bl  + (size_t)(i - 1) * 64;
        const float* gam  = (i == 0) ? g0   : gR  + (size_t)(i - 1) * 64;
        const float* bet  = (i == 0) ? bet0 : betR + (size_t)(i - 1) * 64;
        const int have_gemm = (i < 6);
        float* pool_part = (i == 6) ? partial : nullptr;
        k_layer<<<LAYER_GRID, 256, 0, stream>>>(
            Uin, Vin, hbuf, deg, col64, bias, gam, bet,
            have_gemm ? (BtR + (size_t)i * 128 * 64) : BtR,
            Uout, Vout, batch, pool_part, (i > 0) ? 1 : 0, have_gemm);
        unsigned short* tu = Uin; Uin = Uout; Uout = tu;
        float* tv = Vin; Vin = Vout; Vout = tv;
    }

    k_head<<<1, dim3(32, 32), 0, stream>>>(partial, M0, mb0, mg0, mbe0, M, mb, mg, mbe, Wf, bf, (float*)d_out);
}